// Round 1
// baseline (10872.566 us; speedup 1.0000x reference)
//
#include <hip/hip_runtime.h>
#include <hip/hip_bf16.h>

#define NUM_USERS 100000
#define NUM_ITEMS 50000
#define N_NODES   150000
#define N_EDGES   4000000
#define H         64
#define BATCH     100000
#define MLP_HIDDEN 32

// ---------------------------------------------------------------------------
// Degree count: deg[dst] += 1 for every edge.
__global__ __launch_bounds__(256) void deg_kernel(const int* __restrict__ dst,
                                                  float* __restrict__ deg) {
    int e = blockIdx.x * 256 + threadIdx.x;
    if (e < N_EDGES) unsafeAtomicAdd(&deg[dst[e]], 1.0f);
}

// deg[i] = 1 / max(deg[i], 1)
__global__ __launch_bounds__(256) void recip_kernel(float* __restrict__ deg) {
    int i = blockIdx.x * 256 + threadIdx.x;
    if (i < N_NODES) deg[i] = 1.0f / fmaxf(deg[i], 1.0f);
}

// ---------------------------------------------------------------------------
// Scatter: summed[dst] += x[src].  16 threads per edge, float4 per thread.
__global__ __launch_bounds__(256) void scatter_kernel(const float* __restrict__ x,
                                                      const int* __restrict__ src,
                                                      const int* __restrict__ dst,
                                                      float* __restrict__ summed) {
    int tid = blockIdx.x * 256 + threadIdx.x;
    int e = tid >> 4;
    int p = tid & 15;
    if (e >= N_EDGES) return;
    int s = src[e];
    int d = dst[e];
    const float4 v = *(const float4*)&x[(size_t)s * H + p * 4];
    float* o = &summed[(size_t)d * H + p * 4];
    unsafeAtomicAdd(o + 0, v.x);
    unsafeAtomicAdd(o + 1, v.y);
    unsafeAtomicAdd(o + 2, v.z);
    unsafeAtomicAdd(o + 3, v.w);
}

// ---------------------------------------------------------------------------
// Layer: y = relu(mean @ Wl + bl + x @ Wr), written IN PLACE into sum_io.
// 4 nodes per 256-thread block; Wl/Wr staged in LDS (32 KB).
__global__ __launch_bounds__(256) void sage_layer_kernel(const float* __restrict__ x,
                                                         float* __restrict__ sum_io,
                                                         const float* __restrict__ rdeg,
                                                         const float* __restrict__ Wl,
                                                         const float* __restrict__ bl,
                                                         const float* __restrict__ Wr) {
    __shared__ float sWl[H * H];
    __shared__ float sWr[H * H];
    __shared__ float sMean[4][H];
    __shared__ float sX[4][H];

    for (int i = threadIdx.x; i < H * H; i += 256) {
        sWl[i] = Wl[i];
        sWr[i] = Wr[i];
    }

    int slot = threadIdx.x >> 6;   // 0..3
    int h    = threadIdx.x & 63;   // 0..63
    int node = blockIdx.x * 4 + slot;   // N_NODES % 4 == 0 -> always valid

    float rd = rdeg[node];
    sMean[slot][h] = sum_io[(size_t)node * H + h] * rd;
    sX[slot][h]   = x[(size_t)node * H + h];
    __syncthreads();

    float acc = bl[h];
#pragma unroll
    for (int k = 0; k < H; ++k) {
        acc = fmaf(sMean[slot][k], sWl[k * H + h], acc);
        acc = fmaf(sX[slot][k],    sWr[k * H + h], acc);
    }
    sum_io[(size_t)node * H + h] = fmaxf(acc, 0.0f);
}

// ---------------------------------------------------------------------------
// Final MLP: rating = clip(relu(pair @ W1 + b1) @ W2 + b2, 1, 5)
// 8 batch elements per 256-thread block; 32 threads per element.
__global__ __launch_bounds__(256) void mlp_kernel(const float* __restrict__ x,
                                                  const int* __restrict__ uids,
                                                  const int* __restrict__ iids,
                                                  const float* __restrict__ W1,
                                                  const float* __restrict__ b1,
                                                  const float* __restrict__ W2,
                                                  const float* __restrict__ b2,
                                                  float* __restrict__ out) {
    __shared__ float sW1[2 * H * MLP_HIDDEN];   // 128x32 = 16 KB
    __shared__ float sPair[8][2 * H];
    __shared__ float sW2[MLP_HIDDEN];

    for (int i = threadIdx.x; i < 2 * H * MLP_HIDDEN; i += 256) sW1[i] = W1[i];
    if (threadIdx.x < MLP_HIDDEN) sW2[threadIdx.x] = W2[threadIdx.x];

    int slot = threadIdx.x >> 5;   // 0..7
    int j    = threadIdx.x & 31;   // 0..31
    int b = blockIdx.x * 8 + slot; // BATCH % 8 == 0 -> always valid

    int u  = uids[b];
    int it = iids[b] + NUM_USERS;
    float2 a = *(const float2*)&x[(size_t)u * H + j * 2];
    sPair[slot][j * 2]     = a.x;
    sPair[slot][j * 2 + 1] = a.y;
    float2 c = *(const float2*)&x[(size_t)it * H + j * 2];
    sPair[slot][H + j * 2]     = c.x;
    sPair[slot][H + j * 2 + 1] = c.y;
    __syncthreads();

    float hacc = b1[j];
#pragma unroll
    for (int k = 0; k < 2 * H; ++k)
        hacc = fmaf(sPair[slot][k], sW1[k * MLP_HIDDEN + j], hacc);
    hacc = fmaxf(hacc, 0.0f);

    float r = hacc * sW2[j];
#pragma unroll
    for (int off = 16; off; off >>= 1) r += __shfl_down(r, off, 32);

    if (j == 0) out[b] = fminf(fmaxf(r + b2[0], 1.0f), 5.0f);
}

// ---------------------------------------------------------------------------
extern "C" void kernel_launch(void* const* d_in, const int* in_sizes, int n_in,
                              void* d_out, int out_size, void* d_ws, size_t ws_size,
                              hipStream_t stream) {
    const int*   edge_index = (const int*)d_in[0];   // [2, E]
    const int*   user_ids   = (const int*)d_in[1];
    const int*   item_ids   = (const int*)d_in[2];
    const float* user_emb   = (const float*)d_in[3];
    const float* item_emb   = (const float*)d_in[4];
    const float* Wl         = (const float*)d_in[5]; // [3,64,64]
    const float* bl         = (const float*)d_in[6]; // [3,64]
    const float* Wr         = (const float*)d_in[7]; // [3,64,64]
    const float* W1         = (const float*)d_in[8]; // [128,32]
    const float* b1         = (const float*)d_in[9];
    const float* W2         = (const float*)d_in[10];
    const float* b2         = (const float*)d_in[11];
    float* out = (float*)d_out;

    const int* src = edge_index;            // first row
    const int* dst = edge_index + N_EDGES;  // second row

    const size_t NH = (size_t)N_NODES * H;
    float* bufA = (float*)d_ws;
    float* bufB = bufA + NH;
    float* deg  = bufB + NH;

    // x = concat(user_emb, item_emb) -> bufA
    hipMemcpyAsync(bufA, user_emb, (size_t)NUM_USERS * H * sizeof(float),
                   hipMemcpyDeviceToDevice, stream);
    hipMemcpyAsync(bufA + (size_t)NUM_USERS * H, item_emb,
                   (size_t)NUM_ITEMS * H * sizeof(float),
                   hipMemcpyDeviceToDevice, stream);

    // degree -> reciprocal
    hipMemsetAsync(deg, 0, (size_t)N_NODES * sizeof(float), stream);
    deg_kernel<<<(N_EDGES + 255) / 256, 256, 0, stream>>>(dst, deg);
    recip_kernel<<<(N_NODES + 255) / 256, 256, 0, stream>>>(deg);

    float* x = bufA;
    float* s = bufB;
    for (int l = 0; l < 3; ++l) {
        hipMemsetAsync(s, 0, NH * sizeof(float), stream);
        scatter_kernel<<<(N_EDGES * 16) / 256, 256, 0, stream>>>(x, src, dst, s);
        sage_layer_kernel<<<N_NODES / 4, 256, 0, stream>>>(
            x, s, deg, Wl + (size_t)l * H * H, bl + (size_t)l * H, Wr + (size_t)l * H * H);
        // result of this layer now lives in s; old x becomes next scratch
        float* t = x; x = s; s = t;
    }

    mlp_kernel<<<BATCH / 8, 256, 0, stream>>>(x, user_ids, item_ids, W1, b1, W2, b2, out);
}